// Round 2
// baseline (177.524 us; speedup 1.0000x reference)
//
#include <hip/hip_runtime.h>
#include <math.h>

// Problem constants (from reference)
#define NB 128
#define NT 256
#define NI 256
#define NF 256
#define NROWS (NB * NT)   // 32768 independent rows
#define RPB 16            // rows per block
#define NTHREADS 256
#define TAU 2.5e-4f       // fp32-vs-fp64 ambiguity band half-width

// Key facts (verified R1, absmax == 0.0):
//  * alpha = exp(-50): (1-alpha) rounds to 1.0 and alpha*v_prev underflows vs
//    cur in fp32 AND fp64 -> v_mem(t) == cur(t); the scan decouples.
//  * LayerNorm of binary s collapses: mu = k/256 (exact), var = mu(1-mu).
//  * Spike decision must match the np (fp64) reference exactly; one flip
//    costs ~2.5 absmax vs a 0.067 threshold.
// This round: fp32 bulk dot + fp64 fixup only inside |v-0.5| < TAU.
//  fp32 error bound: 256 fma roundings, partial sums <~4 => |err| <= 6e-5.
//  TAU = 2.5e-4 gives 4x margin; elements outside the band provably decide
//  identically in fp32 and fp64. In-band (~1/4000) get exact fp64 recompute.

__global__ void lif_fused_f32fix(const float* __restrict__ spikes,   // [NROWS, NI]
                                 const float* __restrict__ W,        // [NI, NF]
                                 const float* __restrict__ bias,     // [NF]
                                 const float* __restrict__ ln_scale, // [NT, NF]
                                 const float* __restrict__ ln_bias,  // [NT, NF]
                                 float* __restrict__ out)            // [NROWS, NF]
{
    __shared__ float sf[RPB][NI];   // 16 KB: spike rows (exact input values)
    __shared__ int wcnt[4][RPB];    // per-wave spike counts

    const int tid = threadIdx.x;
    const int row0 = blockIdx.x * RPB;

    // Stage 16 spike rows -> LDS (coalesced)
    #pragma unroll
    for (int r = 0; r < RPB; ++r)
        sf[r][tid] = spikes[(size_t)(row0 + r) * NI + tid];
    __syncthreads();

    const int f = tid;               // this thread owns output column f
    const float bv = bias[f];

    float acc[RPB];
    #pragma unroll
    for (int r = 0; r < RPB; ++r) acc[r] = 0.0f;

    const float* wp = W + f;
    // Bulk fp32 dot: per 4 i's -> 4 coalesced W loads (L2-resident) +
    // 16 broadcast ds_read_b128 + 64 v_fmac_f32.
    for (int i = 0; i < NI; i += 4) {
        const float w0 = wp[(size_t)(i + 0) * NF];
        const float w1 = wp[(size_t)(i + 1) * NF];
        const float w2 = wp[(size_t)(i + 2) * NF];
        const float w3 = wp[(size_t)(i + 3) * NF];
        #pragma unroll
        for (int r = 0; r < RPB; ++r) {
            const float4 s4 = *reinterpret_cast<const float4*>(&sf[r][i]);
            acc[r] = fmaf(s4.x, w0, acc[r]);
            acc[r] = fmaf(s4.y, w1, acc[r]);
            acc[r] = fmaf(s4.z, w2, acc[r]);
            acc[r] = fmaf(s4.w, w3, acc[r]);
        }
    }

    // Spike decision with fp64 fixup in the ambiguity band, then ballot counts
    const int lane = tid & 63;
    const int wid = tid >> 6;
    bool sb[RPB];
    #pragma unroll 1
    for (int r = 0; r < RPB; ++r) {
        const float v = acc[r] + bv;
        bool s;
        if (__builtin_expect(fabsf(v - 0.5f) < TAU, 0)) {
            // rare exact path: fp64 dot from LDS row (exact input values)
            double a0 = 0.0, a1 = 0.0, a2 = 0.0, a3 = 0.0;
            for (int i = 0; i < NI; i += 4) {
                a0 += (double)sf[r][i + 0] * (double)wp[(size_t)(i + 0) * NF];
                a1 += (double)sf[r][i + 1] * (double)wp[(size_t)(i + 1) * NF];
                a2 += (double)sf[r][i + 2] * (double)wp[(size_t)(i + 2) * NF];
                a3 += (double)sf[r][i + 3] * (double)wp[(size_t)(i + 3) * NF];
            }
            const double a = ((a0 + a1) + (a2 + a3)) + (double)bv;
            s = (a - 0.5) > 0.0;
        } else {
            s = (v - 0.5f) > 0.0f;
        }
        sb[r] = s;
        const unsigned long long m = __ballot(s);
        if (lane == 0) wcnt[wid][r] = __popcll(m);
    }
    __syncthreads();

    // Closed-form LayerNorm epilogue (binary s)
    #pragma unroll
    for (int r = 0; r < RPB; ++r) {
        const int row = row0 + r;
        const int t = row & (NT - 1);           // row = b*NT + t
        const int k = wcnt[0][r] + wcnt[1][r] + wcnt[2][r] + wcnt[3][r];
        const double mu = (double)k * (1.0 / 256.0);      // exact
        const double var = mu * (1.0 - mu);               // exact for binary s
        const float rinv = (float)(1.0 / sqrt(var + 1e-6));
        const float g = ln_scale[t * NF + f];
        const float be = ln_bias[t * NF + f];
        const float sv = sb[r] ? 1.0f : 0.0f;
        const float muf = (float)mu;                      // exact in fp32
        out[(size_t)row * NF + f] = (sv - muf) * rinv * g + be;
    }
}

extern "C" void kernel_launch(void* const* d_in, const int* in_sizes, int n_in,
                              void* d_out, int out_size, void* d_ws, size_t ws_size,
                              hipStream_t stream) {
    const float* spikes   = (const float*)d_in[0];
    const float* W        = (const float*)d_in[1];
    const float* bias     = (const float*)d_in[2];
    const float* ln_scale = (const float*)d_in[3];
    const float* ln_bias  = (const float*)d_in[4];
    float* out = (float*)d_out;

    dim3 grid(NROWS / RPB);   // 2048 blocks
    dim3 block(NTHREADS);
    hipLaunchKernelGGL(lif_fused_f32fix, grid, block, 0, stream,
                       spikes, W, bias, ln_scale, ln_bias, out);
}

// Round 3
// 113.240 us; speedup vs baseline: 1.5677x; 1.5677x over previous
//
#include <hip/hip_runtime.h>
#include <math.h>

// ---------------- problem constants ----------------
#define NROWS 32768   // B*T independent rows (scan decouples: alpha=exp(-50))
#define NKDIM 256     // IN_F (K)
#define NFDIM 256     // F   (N)
#define MTILE 64      // rows per block
#define KCH   32      // K per MFMA step
#define NKS   8       // K steps (256/32)
#define TAU   4e-4f   // fp32-split vs fp64 ambiguity band (worst-case err ~1.2e-4)

// Verified facts (R1, absmax == 0.0):
//  * v_mem(t) == cur(t) exactly in the reference's own arithmetic -> rows independent.
//  * LN of binary s collapses: mu = k/256 exact, var = mu(1-mu) exact.
//  * fp64 dot reproduces the np reference's spike decisions exactly.
// This round: bulk GEMM on MFMA with split-bf16 (A: 2 comps, W: 3 comps,
// 5 products), fp64 fixup only inside |v-0.5| < TAU.

typedef __attribute__((ext_vector_type(8))) short bf16x8;
typedef __attribute__((ext_vector_type(4))) float f32x4;

__device__ __forceinline__ unsigned short bf16_rne(float f) {
    unsigned int u = __builtin_bit_cast(unsigned int, f);
    u += 0x7FFFu + ((u >> 16) & 1u);       // round-to-nearest-even
    return (unsigned short)(u >> 16);
}
__device__ __forceinline__ float bf16_to_f32(unsigned short h) {
    unsigned int u = ((unsigned int)h) << 16;
    return __builtin_bit_cast(float, u);
}

// ---------------- kernel 0: split W into 3 bf16 comps, MFMA-B-fragment layout ----
// layout: wt[comp][ks][chunk][col][j]  (shorts), comp stride 65536, ks 8192,
// chunk 2048, col 8.  Element (comp, col, k) with k = ks*32 + chunk*8 + j.
__global__ void split_w(const float* __restrict__ W, unsigned short* __restrict__ wt) {
    const int k = blockIdx.x;       // 0..255
    const int col = threadIdx.x;    // 0..255
    const float w = W[k * NFDIM + col];
    const unsigned short h1 = bf16_rne(w);
    const float r1 = w - bf16_to_f32(h1);
    const unsigned short h2 = bf16_rne(r1);
    const float r2 = r1 - bf16_to_f32(h2);
    const unsigned short h3 = bf16_rne(r2);
    const int ks = k >> 5, chunk = (k >> 3) & 3, j = k & 7;
    const size_t base = ((size_t)ks * 4 + chunk) * 2048 + (size_t)col * 8 + j;
    wt[base]           = h1;
    wt[base + 65536]   = h2;
    wt[base + 131072]  = h3;
}

// ---------------- kernel 1: fused split-GEMM + spike + closed-form LN ----------
__global__ __launch_bounds__(512)
void lif_mfma(const float* __restrict__ spikes,
              const float* __restrict__ W,
              const float* __restrict__ bias,
              const float* __restrict__ ln_scale,
              const float* __restrict__ ln_bias,
              const unsigned short* __restrict__ wt,
              float* __restrict__ out)
{
    // A tile: double-buffered, 2 comps, 64 rows x 32 k bf16, row stride 40
    // shorts (80 B -> 2-way banks on b128 reads = free).
    __shared__ __align__(16) short alds[2][2][MTILE * 40];   // 20.5 KB
    __shared__ unsigned int bits[MTILE][8];                  // 2 KB (256-bit row masks)
    __shared__ float rinv_s[MTILE], mu_s[MTILE];

    const int tid = threadIdx.x;
    const int lane = tid & 63;
    const int wid = tid >> 6;          // 0..7
    const int wm = wid >> 2;           // 0..1: rows [wm*32, +32)
    const int wn = wid & 3;            // 0..3: cols [wn*64, +64)
    const int row0 = blockIdx.x * MTILE;

    // staging map: thread -> (row st_r, k st_k..st_k+3)
    const int st_r = tid >> 3;
    const int st_k = (tid & 7) * 4;
    const float* sp_base = spikes + (size_t)(row0 + st_r) * NKDIM + st_k;
    const int widx = st_r * 40 + st_k;

    // A-frag offsets (shorts): row = wm*32 + mt*16 + (lane&15), chunk = lane>>4
    const int arow = wm * 32 + (lane & 15);
    const int a_off0 = arow * 40 + (lane >> 4) * 8;
    const int a_off1 = (arow + 16) * 40 + (lane >> 4) * 8;

    // B-frag lane offset (shorts): [chunk=lane>>4][col][8]
    const int bcol = wn * 64 + (lane & 15);
    const int b_lane_off = (lane >> 4) * 2048 + bcol * 8;

    // ---- stage k-chunk 0 into buf 0 ----
    {
        const float4 v = *reinterpret_cast<const float4*>(sp_base);
        float fv[4] = {v.x, v.y, v.z, v.w};
        unsigned short h[4], l[4];
        #pragma unroll
        for (int e = 0; e < 4; ++e) {
            h[e] = bf16_rne(fv[e]);
            l[e] = bf16_rne(fv[e] - bf16_to_f32(h[e]));
        }
        *(uint2*)&alds[0][0][widx] = make_uint2(h[0] | (h[1] << 16), h[2] | (h[3] << 16));
        *(uint2*)&alds[0][1][widx] = make_uint2(l[0] | (l[1] << 16), l[2] | (l[3] << 16));
    }
    __syncthreads();

    f32x4 acc[2][4];
    {
        const f32x4 z = {0.f, 0.f, 0.f, 0.f};
        #pragma unroll
        for (int mt = 0; mt < 2; ++mt)
            #pragma unroll
            for (int nt = 0; nt < 4; ++nt) acc[mt][nt] = z;
    }

    // ---- K loop ----
    for (int ks = 0; ks < NKS; ++ks) {
        const int cur = ks & 1;
        float4 vn;
        if (ks < NKS - 1)
            vn = *reinterpret_cast<const float4*>(sp_base + (ks + 1) * KCH);

        // B fragments for this k-step (L2-resident, pre-permuted)
        bf16x8 bf[3][4];
        #pragma unroll
        for (int c = 0; c < 3; ++c)
            #pragma unroll
            for (int nt = 0; nt < 4; ++nt)
                bf[c][nt] = *reinterpret_cast<const bf16x8*>(
                    wt + (size_t)(c * 8 + ks) * 8192 + b_lane_off + nt * 128);

        // A fragments
        const bf16x8 ah0 = *(const bf16x8*)&alds[cur][0][a_off0];
        const bf16x8 ah1 = *(const bf16x8*)&alds[cur][0][a_off1];
        const bf16x8 al0 = *(const bf16x8*)&alds[cur][1][a_off0];
        const bf16x8 al1 = *(const bf16x8*)&alds[cur][1][a_off1];

        // 5 split-products per (mt, nt): ah*b1 + al*b1 + ah*b2 + al*b2 + ah*b3
        #pragma unroll
        for (int nt = 0; nt < 4; ++nt) {
            acc[0][nt] = __builtin_amdgcn_mfma_f32_16x16x32_bf16(ah0, bf[0][nt], acc[0][nt], 0, 0, 0);
            acc[1][nt] = __builtin_amdgcn_mfma_f32_16x16x32_bf16(ah1, bf[0][nt], acc[1][nt], 0, 0, 0);
            acc[0][nt] = __builtin_amdgcn_mfma_f32_16x16x32_bf16(al0, bf[0][nt], acc[0][nt], 0, 0, 0);
            acc[1][nt] = __builtin_amdgcn_mfma_f32_16x16x32_bf16(al1, bf[0][nt], acc[1][nt], 0, 0, 0);
            acc[0][nt] = __builtin_amdgcn_mfma_f32_16x16x32_bf16(ah0, bf[1][nt], acc[0][nt], 0, 0, 0);
            acc[1][nt] = __builtin_amdgcn_mfma_f32_16x16x32_bf16(ah1, bf[1][nt], acc[1][nt], 0, 0, 0);
            acc[0][nt] = __builtin_amdgcn_mfma_f32_16x16x32_bf16(al0, bf[1][nt], acc[0][nt], 0, 0, 0);
            acc[1][nt] = __builtin_amdgcn_mfma_f32_16x16x32_bf16(al1, bf[1][nt], acc[1][nt], 0, 0, 0);
            acc[0][nt] = __builtin_amdgcn_mfma_f32_16x16x32_bf16(ah0, bf[2][nt], acc[0][nt], 0, 0, 0);
            acc[1][nt] = __builtin_amdgcn_mfma_f32_16x16x32_bf16(ah1, bf[2][nt], acc[1][nt], 0, 0, 0);
        }

        // split + write next chunk (waits on vn automatically)
        if (ks < NKS - 1) {
            float fv[4] = {vn.x, vn.y, vn.z, vn.w};
            unsigned short h[4], l[4];
            #pragma unroll
            for (int e = 0; e < 4; ++e) {
                h[e] = bf16_rne(fv[e]);
                l[e] = bf16_rne(fv[e] - bf16_to_f32(h[e]));
            }
            *(uint2*)&alds[cur ^ 1][0][widx] = make_uint2(h[0] | (h[1] << 16), h[2] | (h[3] << 16));
            *(uint2*)&alds[cur ^ 1][1][widx] = make_uint2(l[0] | (l[1] << 16), l[2] | (l[3] << 16));
        }
        __syncthreads();
    }

    // ---- decisions (+ rare fp64 fixup), pack per-lane masks ----
    unsigned int smask[2] = {0u, 0u};   // bit (nt*4 + reg)
    #pragma unroll
    for (int mt = 0; mt < 2; ++mt) {
        #pragma unroll
        for (int nt = 0; nt < 4; ++nt) {
            const int gcol = bcol + nt * 16;
            const float bv = bias[gcol];
            #pragma unroll
            for (int reg = 0; reg < 4; ++reg) {
                const float v = acc[mt][nt][reg] + bv;
                bool s;
                if (__builtin_expect(fabsf(v - 0.5f) < TAU, 0)) {
                    const int grow = row0 + wm * 32 + mt * 16 + (lane >> 4) * 4 + reg;
                    const float* sr = spikes + (size_t)grow * NKDIM;
                    const float* wc = W + gcol;
                    double a0 = 0.0, a1 = 0.0, a2 = 0.0, a3 = 0.0;
                    for (int i = 0; i < NKDIM; i += 4) {
                        a0 += (double)sr[i + 0] * (double)wc[(size_t)(i + 0) * NFDIM];
                        a1 += (double)sr[i + 1] * (double)wc[(size_t)(i + 1) * NFDIM];
                        a2 += (double)sr[i + 2] * (double)wc[(size_t)(i + 2) * NFDIM];
                        a3 += (double)sr[i + 3] * (double)wc[(size_t)(i + 3) * NFDIM];
                    }
                    const double ve = ((a0 + a1) + (a2 + a3)) + (double)bv;
                    s = (ve - 0.5) > 0.0;
                } else {
                    s = (v - 0.5f) > 0.0f;
                }
                if (s) smask[mt] |= 1u << (nt * 4 + reg);
            }
        }
    }

    // ---- assemble 256-bit row masks via ballot ----
    #pragma unroll
    for (int mt = 0; mt < 2; ++mt) {
        #pragma unroll
        for (int reg = 0; reg < 4; ++reg) {
            unsigned long long m[4];
            #pragma unroll
            for (int nt = 0; nt < 4; ++nt)
                m[nt] = __ballot((smask[mt] >> (nt * 4 + reg)) & 1u);
            if (lane < 4) {
                const int g = lane;
                const unsigned int w0 =
                    (unsigned int)((m[0] >> (g * 16)) & 0xFFFFull) |
                    ((unsigned int)((m[1] >> (g * 16)) & 0xFFFFull) << 16);
                const unsigned int w1 =
                    (unsigned int)((m[2] >> (g * 16)) & 0xFFFFull) |
                    ((unsigned int)((m[3] >> (g * 16)) & 0xFFFFull) << 16);
                const int rl = wm * 32 + mt * 16 + g * 4 + reg;
                bits[rl][wn * 2 + 0] = w0;
                bits[rl][wn * 2 + 1] = w1;
            }
        }
    }
    __syncthreads();

    // ---- per-row stats (identical double math to R1) ----
    if (tid < MTILE) {
        int kc = 0;
        #pragma unroll
        for (int w = 0; w < 8; ++w) kc += __popc(bits[tid][w]);
        const double mu = (double)kc * (1.0 / 256.0);
        const double var = mu * (1.0 - mu);
        rinv_s[tid] = (float)(1.0 / sqrt(var + 1e-6));
        mu_s[tid] = (float)mu;
    }
    __syncthreads();

    // ---- LN epilogue + coalesced float4 store ----
    const int orow = tid >> 3;          // 0..63
    const int of0 = (tid & 7) * 4;      // 0..28
    const int grow = row0 + orow;
    const int t = grow & (256 - 1);     // row = b*T + t
    const float rinv = rinv_s[orow];
    const float muf = mu_s[orow];
    #pragma unroll
    for (int j = 0; j < 8; ++j) {
        const int f = of0 + j * 32;
        const unsigned int wb = bits[orow][j];   // f>>5 == j since of0 < 32
        const float4 g4 = *reinterpret_cast<const float4*>(&ln_scale[t * NFDIM + f]);
        const float4 b4 = *reinterpret_cast<const float4*>(&ln_bias[t * NFDIM + f]);
        float4 o;
        {
            const float s0 = ((wb >> (of0 + 0)) & 1u) ? 1.0f : 0.0f;
            const float s1 = ((wb >> (of0 + 1)) & 1u) ? 1.0f : 0.0f;
            const float s2 = ((wb >> (of0 + 2)) & 1u) ? 1.0f : 0.0f;
            const float s3 = ((wb >> (of0 + 3)) & 1u) ? 1.0f : 0.0f;
            o.x = (s0 - muf) * rinv * g4.x + b4.x;
            o.y = (s1 - muf) * rinv * g4.y + b4.y;
            o.z = (s2 - muf) * rinv * g4.z + b4.z;
            o.w = (s3 - muf) * rinv * g4.w + b4.w;
        }
        *reinterpret_cast<float4*>(&out[(size_t)grow * NFDIM + f]) = o;
    }
}

extern "C" void kernel_launch(void* const* d_in, const int* in_sizes, int n_in,
                              void* d_out, int out_size, void* d_ws, size_t ws_size,
                              hipStream_t stream) {
    const float* spikes   = (const float*)d_in[0];
    const float* W        = (const float*)d_in[1];
    const float* bias     = (const float*)d_in[2];
    const float* ln_scale = (const float*)d_in[3];
    const float* ln_bias  = (const float*)d_in[4];
    float* out = (float*)d_out;
    unsigned short* wt = (unsigned short*)d_ws;   // 384 KB

    split_w<<<dim3(256), dim3(256), 0, stream>>>(W, wt);
    lif_mfma<<<dim3(NROWS / MTILE), dim3(512), 0, stream>>>(
        spikes, W, bias, ln_scale, ln_bias, wt, out);
}

// Round 5
// 40.353 us; speedup vs baseline: 4.3992x; 2.8062x over previous
//
#include <hip/hip_runtime.h>
#include <math.h>

// ---------------- problem constants ----------------
#define NROWS 32768   // B*T independent rows (alpha=exp(-50): scan decouples, verified R1)
#define NK 256        // IN_F
#define NF 256        // F
#define NT_SEQ 256    // T
#define MTILE 32      // rows per block
#define TAU 5e-4f     // fp16-split vs fp64 ambiguity band (worst-case err ~2e-4)

// Verified facts (R1/R3, absmax == 0.0):
//  * v_mem(t) == cur(t) exactly in the reference's own arithmetic.
//  * LN of binary s collapses: mu = k/256 exact, var = mu(1-mu).
//  * fp64 dot reproduces the np reference's spike decisions exactly.
//  * MFMA fragment mapping (A: row=lane&15, k=(lane>>4)*8+j; B: col=lane&15,
//    same k; C/D: col=lane&15, row=(lane>>4)*4+reg) is correct (R3 absmax 0).
// This round: fp16 2+2 split (a ~ ah + al/2048, W*16 ~ b1 + b2/2048),
// 3 MFMA products (ah*b1; ah*b2 + al*b1), barrier-free K loop,
// wave-parallel fp64 recheck of the ~4/block in-band elements.

typedef __attribute__((ext_vector_type(4))) float f32x4;
typedef __attribute__((ext_vector_type(8))) _Float16 f16x8;

__device__ __forceinline__ unsigned short f16_bits(float x) {
    return __builtin_bit_cast(unsigned short, (_Float16)x);   // RNE cvt
}

// ---- k0: split W*16 into 2 fp16 comps, MFMA-B-fragment order (R3 layout) ----
// wt[comp][ks][chunk][col][j] shorts; comp stride 65536, ks 8192, chunk 2048.
__global__ void split_w(const float* __restrict__ W, unsigned short* __restrict__ wt) {
    const int k = blockIdx.x;       // 0..255
    const int col = threadIdx.x;    // 0..255
    const float w16 = W[k * NF + col] * 16.0f;     // exact scale by 2^4
    const _Float16 h1 = (_Float16)w16;             // RNE
    const float r = (w16 - (float)h1) * 2048.0f;   // exact (Sterbenz; *2^11)
    const _Float16 h2 = (_Float16)r;               // RNE
    const int ks = k >> 5, chunk = (k >> 3) & 3, j = k & 7;
    const int base = ((ks * 4 + chunk) * 2048) + col * 8 + j;
    wt[base] = __builtin_bit_cast(unsigned short, h1);
    wt[base + 65536] = __builtin_bit_cast(unsigned short, h2);
}

// ---- k1: fused split-GEMM + spike + exact recheck + closed-form LN ----
__global__ __launch_bounds__(512)
void lif_main(const float* __restrict__ spikes,
              const float* __restrict__ W,
              const float* __restrict__ bias,
              const float* __restrict__ ln_scale,
              const float* __restrict__ ln_bias,
              const unsigned short* __restrict__ wt,
              float* __restrict__ out)
{
    // A panel: 2 comps x 32 rows x 256 k, row stride 264 halfs (528 B ->
    // banks r*132 mod 32 = 4r: 2 lanes/bank on frag reads = free).
    __shared__ __align__(16) short alds[2][MTILE][264];   // 33.8 KB
    __shared__ unsigned int bits[MTILE][8];               // 256-bit row masks
    __shared__ float rinv_s[MTILE], mu_s[MTILE];
    __shared__ unsigned int elist[64];                    // in-band worklist
    __shared__ int ecnt;

    const int tid = threadIdx.x;
    const int lane = tid & 63;
    const int wid = tid >> 6;            // 0..7: cols [wid*32, +32)
    const int row0 = blockIdx.x * MTILE;

    if (tid == 0) ecnt = 0;

    // ---- stage full A panel, split to fp16 pairs (one barrier total) ----
    #pragma unroll
    for (int it = 0; it < 4; ++it) {
        const int idx = it * 2048 + tid * 4;
        const int r = idx >> 8, c = idx & 255;
        const float4 v = *reinterpret_cast<const float4*>(
            spikes + (size_t)(row0 + r) * NK + c);
        unsigned short h[4], l[4];
        const float fv[4] = {v.x, v.y, v.z, v.w};
        #pragma unroll
        for (int e = 0; e < 4; ++e) {
            h[e] = f16_bits(fv[e]);
            const float hf = (float)__builtin_bit_cast(_Float16, h[e]);
            l[e] = f16_bits((fv[e] - hf) * 2048.0f);
        }
        *(uint2*)&alds[0][r][c] = make_uint2((unsigned int)h[0] | ((unsigned int)h[1] << 16),
                                             (unsigned int)h[2] | ((unsigned int)h[3] << 16));
        *(uint2*)&alds[1][r][c] = make_uint2((unsigned int)l[0] | ((unsigned int)l[1] << 16),
                                             (unsigned int)l[2] | ((unsigned int)l[3] << 16));
    }
    __syncthreads();

    // ---- barrier-free K loop: 8 steps x 12 MFMA ----
    f32x4 acc0[2][2], acc1[2][2];
    {
        const f32x4 z = {0.f, 0.f, 0.f, 0.f};
        #pragma unroll
        for (int mt = 0; mt < 2; ++mt)
            #pragma unroll
            for (int nt = 0; nt < 2; ++nt) { acc0[mt][nt] = z; acc1[mt][nt] = z; }
    }
    const int a_off = (lane & 15) * 264 + (lane >> 4) * 8;       // halfs
    const int b_off = (lane >> 4) * 2048 + (wid * 32 + (lane & 15)) * 8;
    const short* alds_flat = &alds[0][0][0];

    for (int ks = 0; ks < 8; ++ks) {
        f16x8 bf[2][2];
        #pragma unroll
        for (int c = 0; c < 2; ++c)
            #pragma unroll
            for (int nt = 0; nt < 2; ++nt)
                bf[c][nt] = *reinterpret_cast<const f16x8*>(
                    wt + c * 65536 + ks * 8192 + b_off + nt * 128);
        f16x8 ah[2], al[2];
        #pragma unroll
        for (int mt = 0; mt < 2; ++mt) {
            ah[mt] = *reinterpret_cast<const f16x8*>(
                alds_flat + (mt * 16) * 264 + ks * 32 + a_off);
            al[mt] = *reinterpret_cast<const f16x8*>(
                alds_flat + 8448 + (mt * 16) * 264 + ks * 32 + a_off);
        }
        #pragma unroll
        for (int mt = 0; mt < 2; ++mt)
            #pragma unroll
            for (int nt = 0; nt < 2; ++nt) {
                acc0[mt][nt] = __builtin_amdgcn_mfma_f32_16x16x32_f16(ah[mt], bf[0][nt], acc0[mt][nt], 0, 0, 0);
                acc1[mt][nt] = __builtin_amdgcn_mfma_f32_16x16x32_f16(ah[mt], bf[1][nt], acc1[mt][nt], 0, 0, 0);
                acc1[mt][nt] = __builtin_amdgcn_mfma_f32_16x16x32_f16(al[mt], bf[0][nt], acc1[mt][nt], 0, 0, 0);
            }
    }

    // ---- decisions; in-band elements -> worklist ----
    unsigned int smask[2] = {0u, 0u};   // bit nt*4+reg
    #pragma unroll
    for (int mt = 0; mt < 2; ++mt)
        #pragma unroll
        for (int nt = 0; nt < 2; ++nt) {
            const int gcol = wid * 32 + nt * 16 + (lane & 15);
            const float bv = bias[gcol];
            #pragma unroll
            for (int reg = 0; reg < 4; ++reg) {
                // v = (acc0 + acc1/2048) / 16 + bias
                const float v = fmaf(acc1[mt][nt][reg], 4.8828125e-4f,
                                     acc0[mt][nt][reg]) * 0.0625f + bv;
                if ((v - 0.5f) > 0.0f) smask[mt] |= 1u << (nt * 4 + reg);
                if (__builtin_expect(fabsf(v - 0.5f) < TAU, 0)) {
                    const int rl = mt * 16 + (lane >> 4) * 4 + reg;
                    const int ei = atomicAdd(&ecnt, 1);
                    if (ei < 64) elist[ei] = (unsigned int)((rl << 8) | gcol);
                }
            }
        }

    // ---- assemble row masks ----
    #pragma unroll
    for (int mt = 0; mt < 2; ++mt)
        #pragma unroll
        for (int reg = 0; reg < 4; ++reg) {
            const unsigned long long m0 = __ballot((smask[mt] >> (reg)) & 1u);
            const unsigned long long m1 = __ballot((smask[mt] >> (4 + reg)) & 1u);
            if (lane < 4) {
                const int g = lane;
                const unsigned int w =
                    (unsigned int)((m0 >> (g * 16)) & 0xFFFFull) |
                    ((unsigned int)((m1 >> (g * 16)) & 0xFFFFull) << 16);
                bits[mt * 16 + g * 4 + reg][wid] = w;
            }
        }
    __syncthreads();

    // ---- exact fp64 recheck of in-band elements (wave-parallel, rare) ----
    const int ne = min(ecnt, 64);
    for (int e = wid; e < ne; e += 8) {
        const unsigned int pk = elist[e];
        const int rl = (int)(pk >> 8), gcol = (int)(pk & 255u);
        const float* sr = spikes + (size_t)(row0 + rl) * NK;
        const float* wc = W + gcol;
        const int k0 = lane * 4;
        const double p0 = (double)sr[k0 + 0] * (double)wc[(size_t)(k0 + 0) * NF];
        const double p1 = (double)sr[k0 + 1] * (double)wc[(size_t)(k0 + 1) * NF];
        const double p2 = (double)sr[k0 + 2] * (double)wc[(size_t)(k0 + 2) * NF];
        const double p3 = (double)sr[k0 + 3] * (double)wc[(size_t)(k0 + 3) * NF];
        double pl = (p0 + p1) + (p2 + p3);
        #pragma unroll
        for (int off = 32; off > 0; off >>= 1) pl += __shfl_down(pl, off);
        if (lane == 0) {
            const double vex = pl + (double)bias[gcol];
            const bool sex = (vex - 0.5) > 0.0;
            const bool spv = (bits[rl][gcol >> 5] >> (gcol & 31)) & 1u;
            if (sex != spv) atomicXor(&bits[rl][gcol >> 5], 1u << (gcol & 31));
        }
    }
    __syncthreads();

    // ---- per-row stats (identical double math to R1/R3) ----
    if (tid < MTILE) {
        int kc = 0;
        #pragma unroll
        for (int w = 0; w < 8; ++w) kc += __popc(bits[tid][w]);
        const double mu = (double)kc * (1.0 / 256.0);
        const double var = mu * (1.0 - mu);
        rinv_s[tid] = (float)(1.0 / sqrt(var + 1e-6));
        mu_s[tid] = (float)mu;
    }
    __syncthreads();

    // ---- LN epilogue + coalesced float4 store ----
    const int orow = tid >> 4;           // 0..31
    const int of0 = (tid & 15) * 4;      // 0..60
    const int grow = row0 + orow;
    const int t = grow & (NT_SEQ - 1);
    const float rinv = rinv_s[orow];
    const float muf = mu_s[orow];
    #pragma unroll
    for (int j = 0; j < 4; ++j) {
        const int f = of0 + j * 64;
        const unsigned int wb = bits[orow][f >> 5];
        const int sh = f & 31;
        const float4 g4 = *reinterpret_cast<const float4*>(&ln_scale[t * NF + f]);
        const float4 b4 = *reinterpret_cast<const float4*>(&ln_bias[t * NF + f]);
        float4 o;
        const float s0 = ((wb >> (sh + 0)) & 1u) ? 1.0f : 0.0f;
        const float s1 = ((wb >> (sh + 1)) & 1u) ? 1.0f : 0.0f;
        const float s2 = ((wb >> (sh + 2)) & 1u) ? 1.0f : 0.0f;
        const float s3 = ((wb >> (sh + 3)) & 1u) ? 1.0f : 0.0f;
        o.x = (s0 - muf) * rinv * g4.x + b4.x;
        o.y = (s1 - muf) * rinv * g4.y + b4.y;
        o.z = (s2 - muf) * rinv * g4.z + b4.z;
        o.w = (s3 - muf) * rinv * g4.w + b4.w;
        *reinterpret_cast<float4*>(&out[(size_t)grow * NF + f]) = o;
    }
}

extern "C" void kernel_launch(void* const* d_in, const int* in_sizes, int n_in,
                              void* d_out, int out_size, void* d_ws, size_t ws_size,
                              hipStream_t stream) {
    const float* spikes   = (const float*)d_in[0];
    const float* W        = (const float*)d_in[1];
    const float* bias     = (const float*)d_in[2];
    const float* ln_scale = (const float*)d_in[3];
    const float* ln_bias  = (const float*)d_in[4];
    float* out = (float*)d_out;
    unsigned short* wt = (unsigned short*)d_ws;   // 256 KB

    split_w<<<dim3(256), dim3(256), 0, stream>>>(W, wt);
    lif_main<<<dim3(NROWS / MTILE), dim3(512), 0, stream>>>(
        spikes, W, bias, ln_scale, ln_bias, wt, out);
}

// Round 6
// 36.515 us; speedup vs baseline: 4.8616x; 1.1051x over previous
//
#include <hip/hip_runtime.h>
#include <math.h>

// ---------------- problem constants ----------------
#define NROWS 32768   // B*T independent rows (alpha=exp(-50): scan decouples, verified R1)
#define NK 256        // IN_F
#define NF 256        // F
#define NT_SEQ 256    // T
#define MTILE 64      // rows per block (R6: 32 -> 64, halves B L2 redundancy)
#define TAU 5e-4f     // fp16-split vs fp64 ambiguity band (worst-case err ~2e-4, validated R5)

// Verified facts (R1/R3/R5, absmax == 0.0):
//  * v_mem(t) == cur(t) exactly in the reference's own arithmetic.
//  * LN of binary s collapses: mu = k/256 exact, var = mu(1-mu).
//  * fp64 dot reproduces the np reference's spike decisions exactly.
//  * MFMA fragment mapping (A: row=lane&15, k=(lane>>4)*8+j; B: col=lane&15;
//    C/D: col=lane&15, row=(lane>>4)*4+reg) correct.
//  * fp16 2+2 split (a ~ ah + al/2048, W*16 ~ b1 + b2/2048), 3 MFMA products,
//    TAU=5e-4 recheck band: exact (R5 absmax 0.0).

typedef __attribute__((ext_vector_type(4))) float f32x4;
typedef __attribute__((ext_vector_type(8))) _Float16 f16x8;

__device__ __forceinline__ unsigned short f16_bits(float x) {
    return __builtin_bit_cast(unsigned short, (_Float16)x);   // RNE cvt
}

// ---- k0: split W*16 into 2 fp16 comps, MFMA-B-fragment order ----
// wt[comp][ks][chunk][col][j] shorts; comp stride 65536, ks 8192, chunk 2048.
__global__ void split_w(const float* __restrict__ W, unsigned short* __restrict__ wt) {
    const int k = blockIdx.x;       // 0..255
    const int col = threadIdx.x;    // 0..255
    const float w16 = W[k * NF + col] * 16.0f;     // exact scale by 2^4
    const _Float16 h1 = (_Float16)w16;             // RNE
    const float r = (w16 - (float)h1) * 2048.0f;   // exact (Sterbenz; *2^11)
    const _Float16 h2 = (_Float16)r;               // RNE
    const int ks = k >> 5, chunk = (k >> 3) & 3, j = k & 7;
    const int base = ((ks * 4 + chunk) * 2048) + col * 8 + j;
    wt[base] = __builtin_bit_cast(unsigned short, h1);
    wt[base + 65536] = __builtin_bit_cast(unsigned short, h2);
}

// ---- k1: fused split-GEMM + spike + exact recheck + closed-form LN ----
__global__ __launch_bounds__(512, 4)
void lif_main(const float* __restrict__ spikes,
              const float* __restrict__ W,
              const float* __restrict__ bias,
              const float* __restrict__ ln_scale,
              const float* __restrict__ ln_bias,
              const unsigned short* __restrict__ wt,
              float* __restrict__ out)
{
    // A panel: 2 comps x 64 rows x 256 k, row stride 264 halfs (528 B ->
    // frag-read banks 4r mod 32: 2-way = free).
    __shared__ __align__(16) short alds[2][MTILE][264];   // 67.6 KB
    __shared__ unsigned int bits[MTILE][8];               // 256-bit row masks
    __shared__ float rinv_s[MTILE], mu_s[MTILE];
    __shared__ unsigned int elist[96];                    // in-band worklist
    __shared__ int ecnt;

    const int tid = threadIdx.x;
    const int lane = tid & 63;
    const int wid = tid >> 6;            // 0..7: cols [wid*32, +32)
    const int row0 = blockIdx.x * MTILE;

    if (tid == 0) ecnt = 0;

    // ---- stage full A panel, split to fp16 pairs (one barrier total) ----
    #pragma unroll
    for (int it = 0; it < 8; ++it) {
        const int idx = it * 2048 + tid * 4;
        const int r = idx >> 8, c = idx & 255;
        const float4 v = *reinterpret_cast<const float4*>(
            spikes + (size_t)(row0 + r) * NK + c);
        unsigned short h[4], l[4];
        const float fv[4] = {v.x, v.y, v.z, v.w};
        #pragma unroll
        for (int e = 0; e < 4; ++e) {
            h[e] = f16_bits(fv[e]);
            const float hf = (float)__builtin_bit_cast(_Float16, h[e]);
            l[e] = f16_bits((fv[e] - hf) * 2048.0f);
        }
        *(uint2*)&alds[0][r][c] = make_uint2((unsigned int)h[0] | ((unsigned int)h[1] << 16),
                                             (unsigned int)h[2] | ((unsigned int)h[3] << 16));
        *(uint2*)&alds[1][r][c] = make_uint2((unsigned int)l[0] | ((unsigned int)l[1] << 16),
                                             (unsigned int)l[2] | ((unsigned int)l[3] << 16));
    }
    __syncthreads();

    // ---- barrier-free K loop: 8 steps x 24 MFMA (4 mt x 2 nt x 3 products) ----
    f32x4 acc0[4][2], acc1[4][2];
    {
        const f32x4 z = {0.f, 0.f, 0.f, 0.f};
        #pragma unroll
        for (int mt = 0; mt < 4; ++mt)
            #pragma unroll
            for (int nt = 0; nt < 2; ++nt) { acc0[mt][nt] = z; acc1[mt][nt] = z; }
    }
    const int a_off = (lane & 15) * 264 + (lane >> 4) * 8;       // halfs
    const int b_off = (lane >> 4) * 2048 + (wid * 32 + (lane & 15)) * 8;
    const short* alds_flat = &alds[0][0][0];

    #pragma unroll 2
    for (int ks = 0; ks < 8; ++ks) {
        f16x8 bf[2][2];
        #pragma unroll
        for (int c = 0; c < 2; ++c)
            #pragma unroll
            for (int nt = 0; nt < 2; ++nt)
                bf[c][nt] = *reinterpret_cast<const f16x8*>(
                    wt + c * 65536 + ks * 8192 + b_off + nt * 128);
        f16x8 ah[4], al[4];
        #pragma unroll
        for (int mt = 0; mt < 4; ++mt) {
            ah[mt] = *reinterpret_cast<const f16x8*>(
                alds_flat + (mt * 16) * 264 + ks * 32 + a_off);
            al[mt] = *reinterpret_cast<const f16x8*>(
                alds_flat + 16896 + (mt * 16) * 264 + ks * 32 + a_off);
        }
        #pragma unroll
        for (int mt = 0; mt < 4; ++mt)
            #pragma unroll
            for (int nt = 0; nt < 2; ++nt) {
                acc0[mt][nt] = __builtin_amdgcn_mfma_f32_16x16x32_f16(ah[mt], bf[0][nt], acc0[mt][nt], 0, 0, 0);
                acc1[mt][nt] = __builtin_amdgcn_mfma_f32_16x16x32_f16(ah[mt], bf[1][nt], acc1[mt][nt], 0, 0, 0);
                acc1[mt][nt] = __builtin_amdgcn_mfma_f32_16x16x32_f16(al[mt], bf[0][nt], acc1[mt][nt], 0, 0, 0);
            }
    }

    // ---- decisions; in-band elements -> worklist ----
    unsigned int smask[4] = {0u, 0u, 0u, 0u};   // bit nt*4+reg
    #pragma unroll
    for (int mt = 0; mt < 4; ++mt)
        #pragma unroll
        for (int nt = 0; nt < 2; ++nt) {
            const int gcol = wid * 32 + nt * 16 + (lane & 15);
            const float bv = bias[gcol];
            #pragma unroll
            for (int reg = 0; reg < 4; ++reg) {
                // v = (acc0 + acc1/2048) / 16 + bias
                const float v = fmaf(acc1[mt][nt][reg], 4.8828125e-4f,
                                     acc0[mt][nt][reg]) * 0.0625f + bv;
                if ((v - 0.5f) > 0.0f) smask[mt] |= 1u << (nt * 4 + reg);
                if (__builtin_expect(fabsf(v - 0.5f) < TAU, 0)) {
                    const int rl = mt * 16 + (lane >> 4) * 4 + reg;
                    const int ei = atomicAdd(&ecnt, 1);
                    if (ei < 96) elist[ei] = (unsigned int)((rl << 8) | gcol);
                }
            }
        }

    // ---- assemble row masks ----
    #pragma unroll
    for (int mt = 0; mt < 4; ++mt)
        #pragma unroll
        for (int reg = 0; reg < 4; ++reg) {
            const unsigned long long m0 = __ballot((smask[mt] >> (reg)) & 1u);
            const unsigned long long m1 = __ballot((smask[mt] >> (4 + reg)) & 1u);
            if (lane < 4) {
                const int g = lane;
                const unsigned int w =
                    (unsigned int)((m0 >> (g * 16)) & 0xFFFFull) |
                    ((unsigned int)((m1 >> (g * 16)) & 0xFFFFull) << 16);
                bits[mt * 16 + g * 4 + reg][wid] = w;
            }
        }
    __syncthreads();

    // ---- exact fp64 recheck of in-band elements (wave-parallel, rare) ----
    const int ne = min(ecnt, 96);
    for (int e = wid; e < ne; e += 8) {
        const unsigned int pk = elist[e];
        const int rl = (int)(pk >> 8), gcol = (int)(pk & 255u);
        const float* sr = spikes + (size_t)(row0 + rl) * NK;
        const float* wc = W + gcol;
        const int k0 = lane * 4;
        const double p0 = (double)sr[k0 + 0] * (double)wc[(size_t)(k0 + 0) * NF];
        const double p1 = (double)sr[k0 + 1] * (double)wc[(size_t)(k0 + 1) * NF];
        const double p2 = (double)sr[k0 + 2] * (double)wc[(size_t)(k0 + 2) * NF];
        const double p3 = (double)sr[k0 + 3] * (double)wc[(size_t)(k0 + 3) * NF];
        double pl = (p0 + p1) + (p2 + p3);
        #pragma unroll
        for (int off = 32; off > 0; off >>= 1) pl += __shfl_down(pl, off);
        if (lane == 0) {
            const double vex = pl + (double)bias[gcol];
            const bool sex = (vex - 0.5) > 0.0;
            const bool spv = (bits[rl][gcol >> 5] >> (gcol & 31)) & 1u;
            if (sex != spv) atomicXor(&bits[rl][gcol >> 5], 1u << (gcol & 31));
        }
    }
    __syncthreads();

    // ---- per-row stats (identical double math to R1/R3/R5) ----
    if (tid < MTILE) {
        int kc = 0;
        #pragma unroll
        for (int w = 0; w < 8; ++w) kc += __popc(bits[tid][w]);
        const double mu = (double)kc * (1.0 / 256.0);
        const double var = mu * (1.0 - mu);
        rinv_s[tid] = (float)(1.0 / sqrt(var + 1e-6));
        mu_s[tid] = (float)mu;
    }
    __syncthreads();

    // ---- LN epilogue + coalesced float4 store ----
    const int orow = tid >> 3;           // 0..63
    const int of0 = (tid & 7) * 4;       // 0..28
    const int grow = row0 + orow;
    const int t = grow & (NT_SEQ - 1);
    const float rinv = rinv_s[orow];
    const float muf = mu_s[orow];
    #pragma unroll
    for (int j = 0; j < 8; ++j) {
        const int f = of0 + j * 32;
        const unsigned int wb = bits[orow][j];   // f>>5 == j since of0 < 32
        const int sh = of0;
        const float4 g4 = *reinterpret_cast<const float4*>(&ln_scale[t * NF + f]);
        const float4 b4 = *reinterpret_cast<const float4*>(&ln_bias[t * NF + f]);
        float4 o;
        const float s0 = ((wb >> (sh + 0)) & 1u) ? 1.0f : 0.0f;
        const float s1 = ((wb >> (sh + 1)) & 1u) ? 1.0f : 0.0f;
        const float s2 = ((wb >> (sh + 2)) & 1u) ? 1.0f : 0.0f;
        const float s3 = ((wb >> (sh + 3)) & 1u) ? 1.0f : 0.0f;
        o.x = (s0 - muf) * rinv * g4.x + b4.x;
        o.y = (s1 - muf) * rinv * g4.y + b4.y;
        o.z = (s2 - muf) * rinv * g4.z + b4.z;
        o.w = (s3 - muf) * rinv * g4.w + b4.w;
        *reinterpret_cast<float4*>(&out[(size_t)grow * NF + f]) = o;
    }
}

extern "C" void kernel_launch(void* const* d_in, const int* in_sizes, int n_in,
                              void* d_out, int out_size, void* d_ws, size_t ws_size,
                              hipStream_t stream) {
    const float* spikes   = (const float*)d_in[0];
    const float* W        = (const float*)d_in[1];
    const float* bias     = (const float*)d_in[2];
    const float* ln_scale = (const float*)d_in[3];
    const float* ln_bias  = (const float*)d_in[4];
    float* out = (float*)d_out;
    unsigned short* wt = (unsigned short*)d_ws;   // 256 KB

    split_w<<<dim3(256), dim3(256), 0, stream>>>(W, wt);
    lif_main<<<dim3(NROWS / MTILE), dim3(512), 0, stream>>>(
        spikes, W, bias, ln_scale, ln_bias, wt, out);
}